// Round 1
// baseline (183.644 us; speedup 1.0000x reference)
//
#include <hip/hip_runtime.h>

typedef __bf16 bf16x8 __attribute__((ext_vector_type(8)));
typedef float f32x4 __attribute__((ext_vector_type(4)));
typedef unsigned short ush;

#define DEV __device__ __forceinline__

// B=8, D_MODEL=512, D_COND=768, N_HEADS=8, dh=64, L=4096, L_COND=256

DEV ush f2bf(float x){
  union { float f; unsigned u; } v; v.f = x;
  unsigned r = v.u + 0x7FFFu + ((v.u >> 16) & 1u);   // RNE
  return (ush)(r >> 16);
}

DEV void gload_lds16(const ush* g, ush* l){
  __builtin_amdgcn_global_load_lds(
      (const __attribute__((address_space(1))) unsigned int*)g,
      (__attribute__((address_space(3))) unsigned int*)l, 16, 0, 0);
}

// ---------------- prep: image transpose-convert (b,512,4096)f32 -> (b*4096,512)bf16 ----------------
__global__ __launch_bounds__(256) void tc_kernel(const float* __restrict__ img, ush* __restrict__ xT){
  __shared__ float tile[32][33];
  const int b = blockIdx.z;
  const int l0 = blockIdx.x << 5, c0 = blockIdx.y << 5;
  const int tx = threadIdx.x & 31, ty = threadIdx.x >> 5;
  const float* src = img + ((size_t)b*512 + c0)*4096 + l0;
  #pragma unroll
  for (int i = 0; i < 32; i += 8) tile[ty+i][tx] = src[(size_t)(ty+i)*4096 + tx];
  __syncthreads();
  ush* dst = xT + ((size_t)b*4096 + l0)*512 + c0;
  #pragma unroll
  for (int i = 0; i < 32; i += 8) dst[(size_t)(ty+i)*512 + tx] = f2bf(tile[tx][ty+i]);
}

// ---------------- prep: convert cond + 4 weight matrices to bf16 ----------------
__global__ __launch_bounds__(256) void cvt_kernel(const float* c0,const float* c1,const float* c2,
                                                  const float* c3,const float* c4,
                                                  ush* o0, ush* o1, ush* o2, ush* o3, ush* o4){
  const int N0=1572864, N1=262144, N2=393216, N3=393216, N4=262144;
  const int stride = gridDim.x * blockDim.x;
  for (int i = blockIdx.x*blockDim.x + threadIdx.x; i < N0+N1+N2+N3+N4; i += stride){
    int j = i; const float* s; ush* d;
    if (j < N0){ s=c0; d=o0; }
    else { j-=N0; if (j<N1){s=c1;d=o1;}
      else { j-=N1; if (j<N2){s=c2;d=o2;}
        else { j-=N2; if (j<N3){s=c3;d=o3;} else { j-=N3; s=c4; d=o4; } } } }
    d[j] = f2bf(s[j]);
  }
}

// ---------------- shared GEMM core: C(128x128) = A(rowmajor over K) . B^T(rowmajor over K) ----------------
// 256 threads / 4 waves, BK=64, 16x16x32 bf16 MFMA, XOR-swizzled LDS (T2) fed by
// pre-swizzled global_load_lds width=16 (both-sides-or-neither rule, m231).
DEV void gemm_core(const ush* __restrict__ Ag, long long a_row0, int lda,
                   const ush* __restrict__ Bg, long long b_row0, int ldb,
                   int K, ush* As, ush* Bs, f32x4 acc[4][4])
{
  const int t = threadIdx.x;
  const int lane = t & 63;
  const int wid = t >> 6, wr = wid >> 1, wc = wid & 1;
  #pragma unroll
  for (int mt=0;mt<4;mt++)
    #pragma unroll
    for (int nt=0;nt<4;nt++) acc[mt][nt] = f32x4{0.f,0.f,0.f,0.f};

  const int nk = K >> 6;
  for (int kt = 0; kt < nk; ++kt){
    const int k0 = kt << 6;
    #pragma unroll
    for (int r = 0; r < 4; ++r){
      int idx = (r<<8) + t;
      int row = idx >> 3, slot = idx & 7;
      gload_lds16(Ag + (a_row0 + row)*(long long)lda + k0 + ((slot ^ (row&7))<<3), As + idx*8);
    }
    #pragma unroll
    for (int r = 0; r < 4; ++r){
      int idx = (r<<8) + t;
      int row = idx >> 3, slot = idx & 7;
      gload_lds16(Bg + (b_row0 + row)*(long long)ldb + k0 + ((slot ^ (row&7))<<3), Bs + idx*8);
    }
    __syncthreads();                     // vmcnt drain + barrier (m97 structure)
    #pragma unroll
    for (int kk = 0; kk < 2; ++kk){
      bf16x8 af[4], bfv[4];
      #pragma unroll
      for (int mt=0;mt<4;mt++){
        int row = (wr<<6) + (mt<<4) + (lane & 15);
        int byte = (row<<7) + (kk<<6) + ((lane>>4)<<4);
        byte ^= (row & 7) << 4;
        af[mt] = *(const bf16x8*)((const char*)As + byte);
      }
      #pragma unroll
      for (int nt=0;nt<4;nt++){
        int row = (wc<<6) + (nt<<4) + (lane & 15);
        int byte = (row<<7) + (kk<<6) + ((lane>>4)<<4);
        byte ^= (row & 7) << 4;
        bfv[nt] = *(const bf16x8*)((const char*)Bs + byte);
      }
      #pragma unroll
      for (int mt=0;mt<4;mt++)
        #pragma unroll
        for (int nt=0;nt<4;nt++)
          acc[mt][nt] = __builtin_amdgcn_mfma_f32_16x16x32_bf16(af[mt], bfv[nt], acc[mt][nt], 0,0,0);
    }
    __syncthreads();
  }
}

// ---------------- Q projection: Q = (xT . Wq^T) * 0.125, written as (b,h,l,dh) bf16 ----------------
__global__ __launch_bounds__(256,2) void qproj_kernel(const ush* __restrict__ xT, const ush* __restrict__ Wqb,
                                                      ush* __restrict__ Qg){
  __shared__ ush As[8192], Bs[8192];
  f32x4 acc[4][4];
  const int nb = blockIdx.x & 3, mb = blockIdx.x >> 2;   // M=32768 (256 mb), N=512 (4 nb)
  gemm_core(xT, (long long)mb*128, 512, Wqb, (long long)nb*128, 512, 512, As, Bs, acc);
  const int lane = threadIdx.x & 63, wid = threadIdx.x >> 6, wr = wid>>1, wc = wid&1;
  #pragma unroll
  for (int mt=0;mt<4;mt++)
    #pragma unroll
    for (int nt=0;nt<4;nt++)
      #pragma unroll
      for (int r=0;r<4;r++){
        int m = mb*128 + (wr<<6) + (mt<<4) + ((lane>>4)<<2) + r;
        int n = (nb<<7) + (wc<<6) + (nt<<4) + (lane&15);
        int bb = m >> 12, l = m & 4095, hh = n >> 6, dh = n & 63;
        Qg[(((size_t)(bb*8 + hh)*4096 + l)<<6) + dh] = f2bf(acc[mt][nt][r] * 0.125f);
      }
}

// ---------------- K/V projection: cond . W^T ; K natural (b,j,512), V transposed (b,h,dh,j) ----------------
__global__ __launch_bounds__(256,2) void kvproj_kernel(const ush* __restrict__ cb, const ush* __restrict__ Wkb,
                                                       const ush* __restrict__ Wvb, ush* __restrict__ Kg,
                                                       ush* __restrict__ Vt){
  __shared__ ush As[8192], Bs[8192];
  f32x4 acc[4][4];
  const int which = blockIdx.z;                            // 0=K, 1=V
  const int nb = blockIdx.x & 3, mb = blockIdx.x >> 2;     // M=2048 (16 mb), N=512 (4 nb)
  gemm_core(cb, (long long)mb*128, 768, which ? Wvb : Wkb, (long long)nb*128, 768, 768, As, Bs, acc);
  const int lane = threadIdx.x & 63, wid = threadIdx.x >> 6, wr = wid>>1, wc = wid&1;
  #pragma unroll
  for (int mt=0;mt<4;mt++)
    #pragma unroll
    for (int nt=0;nt<4;nt++)
      #pragma unroll
      for (int r=0;r<4;r++){
        int m = mb*128 + (wr<<6) + (mt<<4) + ((lane>>4)<<2) + r;
        int n = (nb<<7) + (wc<<6) + (nt<<4) + (lane&15);
        int bb = m >> 8, j = m & 255;
        ush val = f2bf(acc[mt][nt][r]);
        if (!which) Kg[(((size_t)(bb*256 + j))<<9) + n] = val;
        else { int hh = n>>6, dh = n&63; Vt[(((size_t)((bb*8+hh)*64 + dh))<<8) + j] = val; }
      }
}

// ---------------- fused attention: per block (b,h,256 queries), 8 waves x 32q ----------------
// LDS: K (256x64 swz, 32KB) + V^T (64x256 swz, 32KB) + per-wave P (16x256 swz, 64KB) = 128KB
__global__ __launch_bounds__(512,2) void attn_kernel(const ush* __restrict__ Qg, const ush* __restrict__ Kg,
                                                     const ush* __restrict__ Vg, const float* __restrict__ mask,
                                                     ush* __restrict__ Oc){
  extern __shared__ char smem[];
  ush* Ks = (ush*)smem;
  ush* Vs = (ush*)(smem + 32768);
  ush* Ps = (ush*)(smem + 65536);
  const int t = threadIdx.x, lane = t & 63, wid = t >> 6;
  const int qb = blockIdx.x, h = blockIdx.y, b = blockIdx.z;

  // stage K tile (rows j: 64 dh = 128B, 8 slots) — pre-swizzled source, linear LDS dest
  #pragma unroll
  for (int r = 0; r < 4; ++r){
    int idx = (r<<9) + t;
    int j = idx >> 3, slot = idx & 7;
    gload_lds16(Kg + ((size_t)(b*256 + j))*512 + h*64 + ((slot ^ (j&7))<<3), Ks + idx*8);
  }
  // stage V^T tile (rows dh: 256 keys = 512B, 32 slots; XOR permutes low 3 slot bits)
  #pragma unroll
  for (int r = 0; r < 4; ++r){
    int idx = (r<<9) + t;
    int dh = idx >> 5, slot = idx & 31;
    gload_lds16(Vg + ((size_t)((b*8 + h)*64 + dh))*256 + ((((slot&7) ^ (dh&7)) | (slot&24))<<3), Vs + idx*8);
  }

  const int q0 = qb*256 + wid*32;
  bf16x8 qf[2][2];                       // Q fragments straight from global (read-once, no reuse)
  #pragma unroll
  for (int mt=0;mt<2;mt++)
    #pragma unroll
    for (int kk=0;kk<2;kk++)
      qf[mt][kk] = *(const bf16x8*)(Qg + (((size_t)(b*8+h)*4096 + q0 + mt*16 + (lane&15))<<6)
                                       + kk*32 + ((lane>>4)<<3));
  __syncthreads();

  ush* Pw = Ps + wid*4096;               // per-wave 8KB P buffer (16 rows x 512B, swizzled)
  #pragma unroll
  for (int mt=0; mt<2; ++mt){
    f32x4 sacc[16];
    #pragma unroll
    for (int nt=0;nt<16;nt++) sacc[nt] = f32x4{0.f,0.f,0.f,0.f};

    // S = (Q/8) . K^T  : lane holds S[q=(lane>>4)*4+r][key=nt*16+(lane&15)]
    #pragma unroll
    for (int kk=0;kk<2;kk++){
      #pragma unroll
      for (int nt=0;nt<16;nt++){
        int krow = (nt<<4) + (lane & 15);
        int byte = (krow<<7) + (kk<<6) + ((lane>>4)<<4);
        byte ^= (krow & 7) << 4;
        bf16x8 kf = *(const bf16x8*)((const char*)Ks + byte);
        sacc[nt] = __builtin_amdgcn_mfma_f32_16x16x32_bf16(qf[mt][kk], kf, sacc[nt], 0,0,0);
      }
    }

    // + attention_mask (b, q, key) fp32
    const float* mrow = mask + ((size_t)b*4096 + q0 + mt*16 + ((lane>>4)<<2))*256 + (lane & 15);
    #pragma unroll
    for (int nt=0;nt<16;nt++)
      #pragma unroll
      for (int r=0;r<4;r++)
        sacc[nt][r] += mrow[(r<<8) + (nt<<4)];

    // softmax over 256 keys: in-lane over 16 nt, cross-lane over the 16-lane group (xor 1,2,4,8)
    float mx[4], sm[4], rl[4];
    #pragma unroll
    for (int r=0;r<4;r++){
      float m = sacc[0][r];
      #pragma unroll
      for (int nt=1;nt<16;nt++) m = fmaxf(m, sacc[nt][r]);
      m = fmaxf(m, __shfl_xor(m, 1, 64));
      m = fmaxf(m, __shfl_xor(m, 2, 64));
      m = fmaxf(m, __shfl_xor(m, 4, 64));
      m = fmaxf(m, __shfl_xor(m, 8, 64));
      mx[r] = m; sm[r] = 0.f;
    }
    #pragma unroll
    for (int nt=0;nt<16;nt++)
      #pragma unroll
      for (int r=0;r<4;r++){
        float p = __expf(sacc[nt][r] - mx[r]);
        sacc[nt][r] = p; sm[r] += p;
      }
    #pragma unroll
    for (int r=0;r<4;r++){
      sm[r] += __shfl_xor(sm[r], 1, 64);
      sm[r] += __shfl_xor(sm[r], 2, 64);
      sm[r] += __shfl_xor(sm[r], 4, 64);
      sm[r] += __shfl_xor(sm[r], 8, 64);
      rl[r] = 1.f / sm[r];
    }

    // P (C-layout) -> wave-private LDS (swizzled) to re-read as PV A-fragments
    #pragma unroll
    for (int nt=0;nt<16;nt++)
      #pragma unroll
      for (int r=0;r<4;r++){
        int qr = ((lane>>4)<<2) + r;
        int byte = (qr<<9) + (((nt<<4) + (lane&15))<<1);
        byte ^= (qr & 7) << 4;
        *(ush*)((char*)Pw + byte) = f2bf(sacc[nt][r]);
      }

    // O = P . V
    f32x4 oacc[4];
    #pragma unroll
    for (int nt=0;nt<4;nt++) oacc[nt] = f32x4{0.f,0.f,0.f,0.f};
    #pragma unroll
    for (int kc=0;kc<8;kc++){
      int qrow = lane & 15;
      int pbyte = (qrow<<9) + (kc<<6) + ((lane>>4)<<4);
      pbyte ^= (qrow & 7) << 4;
      bf16x8 pf = *(const bf16x8*)((const char*)Pw + pbyte);
      #pragma unroll
      for (int nt=0;nt<4;nt++){
        int dr = (nt<<4) + (lane & 15);
        int vbyte = (dr<<9) + (kc<<6) + ((lane>>4)<<4);
        vbyte ^= (dr & 7) << 4;
        bf16x8 vf = *(const bf16x8*)((const char*)Vs + vbyte);
        oacc[nt] = __builtin_amdgcn_mfma_f32_16x16x32_bf16(pf, vf, oacc[nt], 0,0,0);
      }
    }
    // normalize and store O as (b, l, 512) bf16
    #pragma unroll
    for (int nt=0;nt<4;nt++)
      #pragma unroll
      for (int r=0;r<4;r++){
        int q = q0 + mt*16 + ((lane>>4)<<2) + r;
        Oc[(((size_t)b*4096 + q)<<9) + h*64 + (nt<<4) + (lane&15)] = f2bf(oacc[nt][r] * rl[r]);
      }
  }
}

// ---------------- output projection: out[b] = Wo . Oc[b]^T + bo  (fp32 out, natural layout) ----------------
__global__ __launch_bounds__(256,2) void oproj_kernel(const ush* __restrict__ Wob, const ush* __restrict__ Oc,
                                                      const float* __restrict__ bo, float* __restrict__ out){
  __shared__ ush As[8192], Bs[8192];
  f32x4 acc[4][4];
  const int bz = blockIdx.z;
  const int mb = blockIdx.x >> 5, nb = blockIdx.x & 31;    // M=512 (4 mb), N=4096 (32 nb)
  gemm_core(Wob, (long long)mb*128, 512, Oc + (size_t)bz*4096*512, (long long)nb*128, 512, 512, As, Bs, acc);
  const int lane = threadIdx.x & 63, wid = threadIdx.x >> 6, wr = wid>>1, wc = wid&1;
  #pragma unroll
  for (int mt=0;mt<4;mt++)
    #pragma unroll
    for (int nt=0;nt<4;nt++){
      #pragma unroll
      for (int r=0;r<4;r++){
        int m = (mb<<7) + (wr<<6) + (mt<<4) + ((lane>>4)<<2) + r;
        int n = (nb<<7) + (wc<<6) + (nt<<4) + (lane&15);
        out[(((size_t)(bz*512 + m))<<12) + n] = acc[mt][nt][r] + bo[m];
      }
    }
}

extern "C" void kernel_launch(void* const* d_in, const int* in_sizes, int n_in,
                              void* d_out, int out_size, void* d_ws, size_t ws_size,
                              hipStream_t stream){
  const float* image = (const float*)d_in[0];
  const float* cond  = (const float*)d_in[1];
  const float* mask  = (const float*)d_in[2];
  const float* Wq    = (const float*)d_in[3];
  const float* Wk    = (const float*)d_in[4];
  const float* Wv    = (const float*)d_in[5];
  const float* Wo    = (const float*)d_in[6];
  const float* bo    = (const float*)d_in[7];
  float* out = (float*)d_out;

  char* ws = (char*)d_ws;
  ush* xT   = (ush*)(ws);                       // 33,554,432 B  (b*4096, 512) bf16
  ush* Oc   = xT;                               // aliased: xT dead after qproj
  ush* Qg   = (ush*)(ws + 33554432);            // 33,554,432 B  (b,h,l,dh) bf16
  ush* cndb = (ush*)(ws + 67108864);            //  3,145,728 B
  ush* Kg   = (ush*)(ws + 70254592);            //  2,097,152 B  (b,j,512)
  ush* Vt   = (ush*)(ws + 72351744);            //  2,097,152 B  (b,h,dh,j)
  ush* Wqb  = (ush*)(ws + 74448896);            //    524,288 B
  ush* Wkb  = (ush*)(ws + 74973184);            //    786,432 B
  ush* Wvb  = (ush*)(ws + 75759616);            //    786,432 B
  ush* Wob  = (ush*)(ws + 76546048);            //    524,288 B  — total 77,070,336 B

  (void)hipFuncSetAttribute((const void*)attn_kernel,
                            hipFuncAttributeMaxDynamicSharedMemorySize, 131072);

  tc_kernel<<<dim3(128,16,8), 256, 0, stream>>>(image, xT);
  cvt_kernel<<<dim3(1024), 256, 0, stream>>>(cond, Wq, Wk, Wv, Wo, cndb, Wqb, Wkb, Wvb, Wob);
  qproj_kernel<<<dim3(1024), 256, 0, stream>>>(xT, Wqb, Qg);
  kvproj_kernel<<<dim3(64,1,2), 256, 0, stream>>>(cndb, Wkb, Wvb, Kg, Vt);
  attn_kernel<<<dim3(16,8,8), 512, 131072, stream>>>(Qg, Kg, Vt, mask, Oc);
  oproj_kernel<<<dim3(128,1,8), 256, 0, stream>>>(Wob, Oc, bo, out);
}